// Round 1
// baseline (682.756 us; speedup 1.0000x reference)
//
#include <hip/hip_runtime.h>
#include <cstddef>
#include <cstdint>

#define NB 64
#define ND 1024
#define NO 31
#define NSTEPS 16
#define KS 124           // k-splits (k-chunk = 256 k-units, never crosses an opcode)
#define KT32 992         // total K32 steps = 31*1024/32
#define KC32 8           // K32 steps per block

typedef _Float16 half8 __attribute__((ext_vector_type(8)));
typedef float floatx4 __attribute__((ext_vector_type(4)));

// ---------------- softmax over opcode logits: W[b][t][o] ----------------
__global__ void softmax_k(const float* __restrict__ logits, float* __restrict__ W) {
    int row = blockIdx.x * blockDim.x + threadIdx.x;  // row = b*16 + t
    if (row >= NB * NSTEPS) return;
    const float* x = logits + (size_t)row * NO;
    float m = -1e30f;
    for (int o = 0; o < NO; ++o) m = fmaxf(m, x[o]);
    float e[NO]; float s = 0.f;
    for (int o = 0; o < NO; ++o) { e[o] = expf(x[o] - m); s += e[o]; }
    float inv = 1.0f / s;
    float* wo = W + (size_t)row * NO;
    for (int o = 0; o < NO; ++o) wo[o] = e[o] * inv;
}

// ---- kconv: Ktf fragment-ordered fp16 B ----
// half8 unit index: (ns*KT32 + kt)*64 + l ; element j of that half8 =
//   B[k][n] with k = kt*32 + (l>>4)*8 + j, n = ns*16 + (l&15),
//   B[k][n] = K[o = k>>10][d = k&1023][n]
__global__ void kconv_k(const float* __restrict__ K, _Float16* __restrict__ Ktf) {
    int gid = blockIdx.x * 256 + threadIdx.x;   // total = 64*992*64 = 4,063,232
    int l  = gid & 63;
    int kt = (gid >> 6) % KT32;
    int ns = gid / (64 * KT32);
    int kbase = kt * 32 + (l >> 4) * 8;         // o constant across the 8 j's
    int n  = ns * 16 + (l & 15);
    int o  = kbase >> 10;
    int d0 = kbase & 1023;
    const float* src = K + ((size_t)o << 20) + (size_t)d0 * ND + n;
    half8 v;
    #pragma unroll
    for (int j = 0; j < 8; ++j) v[j] = (_Float16)src[(size_t)j * ND];
    *(half8*)(Ktf + (size_t)gid * 8) = v;
}

// ---- GEMM: P[ks][b][n] = sum over block's 256-k chunk of (w*h) @ B ----
// grid (8 n-tiles of 128, 124 k-splits) = 992 blocks, 256 thr.
// Wave = M64 x N32. A staged once per block into 32 KiB LDS (frag-ordered);
// B streamed global->reg (L3-resident after step 1).
__global__ __launch_bounds__(256, 4) void gemm_k(
    const float* __restrict__ h, const _Float16* __restrict__ Ktf,
    const float* __restrict__ W, float* __restrict__ P, int step)
{
    __shared__ _Float16 lds_a[64 * 256];   // 32 KiB; half8-index: p*64 + b (p = s*4+q)
    int nb = blockIdx.x;                   // 0..7
    int ks = blockIdx.y;                   // 0..123
    int tid = threadIdx.x;
    int l = tid & 63, w = tid >> 6;
    int o = ks >> 2;
    int d_base = (ks & 3) * 256;

    // ---- stage A: fp32 h * w  ->  fp16, frag-ordered ----
    {
        int b = tid >> 2, u = tid & 3;
        float wv = W[((size_t)b * NSTEPS + step) * NO + o];
        const float* hb = h + (size_t)b * ND + d_base;
        #pragma unroll
        for (int li = 0; li < 8; ++li) {
            int p = li * 4 + u;                       // p = s*4+q, d offset = p*8
            float4 x0 = *(const float4*)(hb + p * 8);
            float4 x1 = *(const float4*)(hb + p * 8 + 4);
            half8 v;
            v[0] = (_Float16)(x0.x * wv); v[1] = (_Float16)(x0.y * wv);
            v[2] = (_Float16)(x0.z * wv); v[3] = (_Float16)(x0.w * wv);
            v[4] = (_Float16)(x1.x * wv); v[5] = (_Float16)(x1.y * wv);
            v[6] = (_Float16)(x1.z * wv); v[7] = (_Float16)(x1.w * wv);
            *(half8*)&lds_a[(size_t)(p * 64 + b) * 8] = v;
        }
    }
    __syncthreads();

    int ml = l & 15, q = l >> 4;
    int ns0 = nb * 8 + w * 2;                 // two n-subtiles of 16 per wave
    const half8* Bp0 = (const half8*)Ktf + ((size_t)ns0 * KT32 + (size_t)ks * KC32) * 64 + l;
    const half8* Bp1 = (const half8*)Ktf + ((size_t)(ns0 + 1) * KT32 + (size_t)ks * KC32) * 64 + l;
    const half8* Ap  = (const half8*)lds_a;

    floatx4 acc[2][4] = {};
    #pragma unroll 4
    for (int s = 0; s < KC32; ++s) {
        half8 b0 = Bp0[(size_t)s * 64];
        half8 b1 = Bp1[(size_t)s * 64];
        int abase = (s * 4 + q) * 64 + ml;
        half8 a0 = Ap[abase];
        half8 a1 = Ap[abase + 16];
        half8 a2 = Ap[abase + 32];
        half8 a3 = Ap[abase + 48];
        acc[0][0] = __builtin_amdgcn_mfma_f32_16x16x32_f16(a0, b0, acc[0][0], 0, 0, 0);
        acc[0][1] = __builtin_amdgcn_mfma_f32_16x16x32_f16(a1, b0, acc[0][1], 0, 0, 0);
        acc[0][2] = __builtin_amdgcn_mfma_f32_16x16x32_f16(a2, b0, acc[0][2], 0, 0, 0);
        acc[0][3] = __builtin_amdgcn_mfma_f32_16x16x32_f16(a3, b0, acc[0][3], 0, 0, 0);
        acc[1][0] = __builtin_amdgcn_mfma_f32_16x16x32_f16(a0, b1, acc[1][0], 0, 0, 0);
        acc[1][1] = __builtin_amdgcn_mfma_f32_16x16x32_f16(a1, b1, acc[1][1], 0, 0, 0);
        acc[1][2] = __builtin_amdgcn_mfma_f32_16x16x32_f16(a2, b1, acc[1][2], 0, 0, 0);
        acc[1][3] = __builtin_amdgcn_mfma_f32_16x16x32_f16(a3, b1, acc[1][3], 0, 0, 0);
    }

    // ---- epilogue: C/D col = l&15, row = (l>>4)*4 + r (verified mapping) ----
    float* Pks = P + (size_t)ks * (NB * ND);
    #pragma unroll
    for (int nsub = 0; nsub < 2; ++nsub) {
        int n = (ns0 + nsub) * 16 + ml;
        #pragma unroll
        for (int mt = 0; mt < 4; ++mt) {
            #pragma unroll
            for (int r = 0; r < 4; ++r) {
                int b = mt * 16 + q * 4 + r;
                Pks[(size_t)b * ND + n] = acc[nsub][mt][r];
            }
        }
    }
}

// ---- reduce KS partials + gated update (float2-vectorized) ----
__global__ void update_k(const float* __restrict__ hin, const float* __restrict__ P,
                         const float* __restrict__ operands, float* __restrict__ hout,
                         int step)
{
    int idx = blockIdx.x * blockDim.x + threadIdx.x;   // 32768 threads, float2 each
    int b = idx >> 9, n = (idx & 511) << 1;
    float gl = operands[((size_t)b * NSTEPS + step) * 4 + 3];
    float g  = 1.0f / (1.0f + expf(-gl));
    const float2* p = (const float2*)(P + (size_t)b * ND + n);
    float sx = 0.f, sy = 0.f;
    #pragma unroll 4
    for (int ks = 0; ks < KS; ++ks) {
        float2 v = p[(size_t)ks * (NB * ND / 2)];
        sx += v.x; sy += v.y;
    }
    const float2 hv = *(const float2*)(hin + (size_t)b * ND + n);
    float2 o2;
    o2.x = g * sx + (1.0f - g) * hv.x;
    o2.y = g * sy + (1.0f - g) * hv.y;
    *(float2*)(hout + (size_t)b * ND + n) = o2;
}

extern "C" void kernel_launch(void* const* d_in, const int* in_sizes, int n_in,
                              void* d_out, int out_size, void* d_ws, size_t ws_size,
                              hipStream_t stream)
{
    const float* logits   = (const float*)d_in[0];  // (64,16,31)
    const float* operands = (const float*)d_in[1];  // (64,16,4)
    const float* signal   = (const float*)d_in[2];  // (64,1024)
    const float* opk      = (const float*)d_in[3];  // (31,1024,1024)
    float* out = (float*)d_out;
    char* ws = (char*)d_ws;

    size_t offW = 0;                                   // 128 KB
    size_t offP = 131072;                              // KS*64*1024*4 = 31 MB
    size_t offH = offP + (size_t)KS * NB * ND * 4;
    size_t offK = offH + 2ull * NB * ND * 4;           // Ktf: 62 MiB fp16

    float*    W  = (float*)(ws + offW);
    float*    P  = (float*)(ws + offP);
    float*    h0 = (float*)(ws + offH);
    float*    h1 = h0 + NB * ND;
    _Float16* Ktf = (_Float16*)(ws + offK);

    softmax_k<<<dim3(4), 256, 0, stream>>>(logits, W);
    kconv_k<<<dim3(15872), 256, 0, stream>>>(opk, Ktf);

    const float* hc = signal;
    float* hn = h0;
    for (int t = 0; t < NSTEPS; ++t) {
        gemm_k<<<dim3(8, KS), 256, 0, stream>>>(hc, Ktf, W, P, t);
        float* dst = (t == NSTEPS - 1) ? out : hn;
        update_k<<<dim3(128), 256, 0, stream>>>(hc, P, operands, dst, t);
        hc = dst;
        hn = (hn == h0) ? h1 : h0;
    }
}

// Round 2
// 592.177 us; speedup vs baseline: 1.1530x; 1.1530x over previous
//
#include <hip/hip_runtime.h>
#include <cstddef>
#include <cstdint>

#define NB 64
#define ND 1024
#define NO 31
#define NSTEPS 16
#define KS 124           // k-splits (k-chunk = 256 k-units, never crosses an opcode)
#define KT32 992         // total K32 steps = 31*1024/32
#define KC32 8           // K32 steps per block

typedef _Float16 half8 __attribute__((ext_vector_type(8)));
typedef float floatx4 __attribute__((ext_vector_type(4)));

// ---------------- softmax over opcode logits: W[b][t][o] ----------------
__global__ void softmax_k(const float* __restrict__ logits, float* __restrict__ W) {
    int row = blockIdx.x * blockDim.x + threadIdx.x;  // row = b*16 + t
    if (row >= NB * NSTEPS) return;
    const float* x = logits + (size_t)row * NO;
    float m = -1e30f;
    for (int o = 0; o < NO; ++o) m = fmaxf(m, x[o]);
    float e[NO]; float s = 0.f;
    for (int o = 0; o < NO; ++o) { e[o] = expf(x[o] - m); s += e[o]; }
    float inv = 1.0f / s;
    float* wo = W + (size_t)row * NO;
    for (int o = 0; o < NO; ++o) wo[o] = e[o] * inv;
}

// ---- kconv: Ktf fragment-ordered fp16 B ----
// half8 unit index: (ns*KT32 + kt)*64 + l ; element j of that half8 =
//   B[k][n] with k = kt*32 + (l>>4)*8 + j, n = ns*16 + (l&15),
//   B[k][n] = K[o = k>>10][d = k&1023][n]
__global__ void kconv_k(const float* __restrict__ K, _Float16* __restrict__ Ktf) {
    int gid = blockIdx.x * 256 + threadIdx.x;   // total = 64*992*64 = 4,063,232
    int l  = gid & 63;
    int kt = (gid >> 6) % KT32;
    int ns = gid / (64 * KT32);
    int kbase = kt * 32 + (l >> 4) * 8;         // o constant across the 8 j's
    int n  = ns * 16 + (l & 15);
    int o  = kbase >> 10;
    int d0 = kbase & 1023;
    const float* src = K + ((size_t)o << 20) + (size_t)d0 * ND + n;
    half8 v;
    #pragma unroll
    for (int j = 0; j < 8; ++j) v[j] = (_Float16)src[(size_t)j * ND];
    *(half8*)(Ktf + (size_t)gid * 8) = v;
}

// ---- GEMM: P[ks][b][n] = sum over block's 256-k chunk of (w*h) @ B ----
// grid (8 n-tiles of 128, 124 k-splits) = 992 blocks, 256 thr.
// Wave = M64 x N32. A staged once per block into 32 KiB LDS (frag-ordered);
// B fully preloaded to registers (16 outstanding loads) before MFMA loop.
__global__ __launch_bounds__(256, 4) void gemm_k(
    const float* __restrict__ h, const _Float16* __restrict__ Ktf,
    const float* __restrict__ W, float* __restrict__ P, int step)
{
    __shared__ _Float16 lds_a[64 * 256];   // 32 KiB; half8-index: p*64 + b (p = s*4+q)
    int nb = blockIdx.x;                   // 0..7
    int ks = blockIdx.y;                   // 0..123
    int tid = threadIdx.x;
    int l = tid & 63, w = tid >> 6;
    int o = ks >> 2;
    int d_base = (ks & 3) * 256;

    // ---- stage A: fp32 h * w  ->  fp16, frag-ordered ----
    {
        int b = tid >> 2, u = tid & 3;
        float wv = W[((size_t)b * NSTEPS + step) * NO + o];
        const float* hb = h + (size_t)b * ND + d_base;
        #pragma unroll
        for (int li = 0; li < 8; ++li) {
            int p = li * 4 + u;                       // p = s*4+q, d offset = p*8
            float4 x0 = *(const float4*)(hb + p * 8);
            float4 x1 = *(const float4*)(hb + p * 8 + 4);
            half8 v;
            v[0] = (_Float16)(x0.x * wv); v[1] = (_Float16)(x0.y * wv);
            v[2] = (_Float16)(x0.z * wv); v[3] = (_Float16)(x0.w * wv);
            v[4] = (_Float16)(x1.x * wv); v[5] = (_Float16)(x1.y * wv);
            v[6] = (_Float16)(x1.z * wv); v[7] = (_Float16)(x1.w * wv);
            *(half8*)&lds_a[(size_t)(p * 64 + b) * 8] = v;
        }
    }
    __syncthreads();

    int ml = l & 15, q = l >> 4;
    int ns0 = nb * 8 + w * 2;                 // two n-subtiles of 16 per wave
    const half8* Bp0 = (const half8*)Ktf + ((size_t)ns0 * KT32 + (size_t)ks * KC32) * 64 + l;
    const half8* Bp1 = Bp0 + (size_t)KT32 * 64;   // ns0+1 region
    const half8* Ap  = (const half8*)lds_a;

    floatx4 acc[2][4] = {};

    // preload ALL B fragments: 16 independent 1KB wave-loads in flight
#define LOADB(n0, n1, S) half8 n0 = Bp0[(S) * 64]; half8 n1 = Bp1[(S) * 64];
    LOADB(b00, b01, 0) LOADB(b10, b11, 1) LOADB(b20, b21, 2) LOADB(b30, b31, 3)
    LOADB(b40, b41, 4) LOADB(b50, b51, 5) LOADB(b60, b61, 6) LOADB(b70, b71, 7)
#undef LOADB

#define STEP(n0, n1, S) { \
    int abase = ((S) * 4 + q) * 64 + ml; \
    half8 a0 = Ap[abase]; \
    half8 a1 = Ap[abase + 16]; \
    half8 a2 = Ap[abase + 32]; \
    half8 a3 = Ap[abase + 48]; \
    acc[0][0] = __builtin_amdgcn_mfma_f32_16x16x32_f16(a0, n0, acc[0][0], 0, 0, 0); \
    acc[0][1] = __builtin_amdgcn_mfma_f32_16x16x32_f16(a1, n0, acc[0][1], 0, 0, 0); \
    acc[0][2] = __builtin_amdgcn_mfma_f32_16x16x32_f16(a2, n0, acc[0][2], 0, 0, 0); \
    acc[0][3] = __builtin_amdgcn_mfma_f32_16x16x32_f16(a3, n0, acc[0][3], 0, 0, 0); \
    acc[1][0] = __builtin_amdgcn_mfma_f32_16x16x32_f16(a0, n1, acc[1][0], 0, 0, 0); \
    acc[1][1] = __builtin_amdgcn_mfma_f32_16x16x32_f16(a1, n1, acc[1][1], 0, 0, 0); \
    acc[1][2] = __builtin_amdgcn_mfma_f32_16x16x32_f16(a2, n1, acc[1][2], 0, 0, 0); \
    acc[1][3] = __builtin_amdgcn_mfma_f32_16x16x32_f16(a3, n1, acc[1][3], 0, 0, 0); \
    }
    STEP(b00, b01, 0) STEP(b10, b11, 1) STEP(b20, b21, 2) STEP(b30, b31, 3)
    STEP(b40, b41, 4) STEP(b50, b51, 5) STEP(b60, b61, 6) STEP(b70, b71, 7)
#undef STEP

    // ---- epilogue: C/D col = l&15, row = (l>>4)*4 + r (verified mapping) ----
    float* Pks = P + (size_t)ks * (NB * ND);
    #pragma unroll
    for (int nsub = 0; nsub < 2; ++nsub) {
        int n = (ns0 + nsub) * 16 + ml;
        #pragma unroll
        for (int mt = 0; mt < 4; ++mt) {
            #pragma unroll
            for (int r = 0; r < 4; ++r) {
                int b = mt * 16 + q * 4 + r;
                Pks[(size_t)b * ND + n] = acc[nsub][mt][r];
            }
        }
    }
}

// ---- reduce KS partials + gated update: wave-split ks reduction ----
// 1024 blocks x 256 thr. Block owns 64 contiguous outputs (one b each).
// Wave w sums ks in [31w, 31w+31); lanes map to consecutive outputs
// (coalesced 256B wave-loads). LDS tree combine, first 64 lanes finalize.
__global__ void update_k(const float* __restrict__ hin, const float* __restrict__ P,
                         const float* __restrict__ operands, float* __restrict__ hout,
                         int step)
{
    __shared__ float red[256];
    int tid = threadIdx.x;
    int w = tid >> 6, o = tid & 63;
    int gbase = blockIdx.x * 64;          // 64 outputs per block, same b
    int g = gbase + o;
    const float* p = P + (size_t)(w * 31) * (NB * ND) + g;
    float s = 0.f;
    #pragma unroll
    for (int i = 0; i < 31; ++i) s += p[(size_t)i * (NB * ND)];
    red[tid] = s;
    __syncthreads();
    if (tid < 64) {
        float tot = red[tid] + red[tid + 64] + red[tid + 128] + red[tid + 192];
        int b = g >> 10;
        float gl = operands[((size_t)b * NSTEPS + step) * 4 + 3];
        float gt = 1.0f / (1.0f + expf(-gl));
        hout[g] = gt * tot + (1.0f - gt) * hin[g];
    }
}

extern "C" void kernel_launch(void* const* d_in, const int* in_sizes, int n_in,
                              void* d_out, int out_size, void* d_ws, size_t ws_size,
                              hipStream_t stream)
{
    const float* logits   = (const float*)d_in[0];  // (64,16,31)
    const float* operands = (const float*)d_in[1];  // (64,16,4)
    const float* signal   = (const float*)d_in[2];  // (64,1024)
    const float* opk      = (const float*)d_in[3];  // (31,1024,1024)
    float* out = (float*)d_out;
    char* ws = (char*)d_ws;

    size_t offW = 0;                                   // 128 KB
    size_t offP = 131072;                              // KS*64*1024*4 = 31 MB
    size_t offH = offP + (size_t)KS * NB * ND * 4;
    size_t offK = offH + 2ull * NB * ND * 4;           // Ktf: 62 MiB fp16

    float*    W  = (float*)(ws + offW);
    float*    P  = (float*)(ws + offP);
    float*    h0 = (float*)(ws + offH);
    float*    h1 = h0 + NB * ND;
    _Float16* Ktf = (_Float16*)(ws + offK);

    softmax_k<<<dim3(4), 256, 0, stream>>>(logits, W);
    kconv_k<<<dim3(15872), 256, 0, stream>>>(opk, Ktf);

    const float* hc = signal;
    float* hn = h0;
    for (int t = 0; t < NSTEPS; ++t) {
        gemm_k<<<dim3(8, KS), 256, 0, stream>>>(hc, Ktf, W, P, t);
        float* dst = (t == NSTEPS - 1) ? out : hn;
        update_k<<<dim3(1024), 256, 0, stream>>>(hc, P, operands, dst, t);
        hc = dst;
        hn = (hn == h0) ? h1 : h0;
    }
}

// Round 3
// 585.961 us; speedup vs baseline: 1.1652x; 1.0106x over previous
//
#include <hip/hip_runtime.h>
#include <cstddef>
#include <cstdint>

#define NB 64
#define ND 1024
#define NO 31
#define NSTEPS 16
#define KS 124           // k-splits (k-chunk = 256 k-units, never crosses an opcode)
#define KT32 992         // total K32 steps = 31*1024/32
#define KC32 8           // K32 steps per block

typedef _Float16 half8 __attribute__((ext_vector_type(8)));
typedef float floatx4 __attribute__((ext_vector_type(4)));

// ---------------- softmax over opcode logits: W[b][t][o] ----------------
__global__ void softmax_k(const float* __restrict__ logits, float* __restrict__ W) {
    int row = blockIdx.x * blockDim.x + threadIdx.x;  // row = b*16 + t
    if (row >= NB * NSTEPS) return;
    const float* x = logits + (size_t)row * NO;
    float m = -1e30f;
    for (int o = 0; o < NO; ++o) m = fmaxf(m, x[o]);
    float e[NO]; float s = 0.f;
    for (int o = 0; o < NO; ++o) { e[o] = expf(x[o] - m); s += e[o]; }
    float inv = 1.0f / s;
    float* wo = W + (size_t)row * NO;
    for (int o = 0; o < NO; ++o) wo[o] = e[o] * inv;
}

// ---- kconv v2: coalesced tile transpose ----
// Block = one kt (32 k-rows, never crosses opcode) x 256 n-cols.
// Phase 1: float4 row loads (1KB/wave contiguous) -> LDS, bit4-XOR swizzle.
// Phase 2: column gather (2-way bank alias = free), cvt fp16, contiguous
// 1KB wave-stores in fragment order.
// Ktf half8 unit (ns*KT32 + kt)*64 + l holds k = kt*32 + (l>>4)*8 + j,
// n = ns*16 + (l&15); value = K[k*1024 + n].
__global__ __launch_bounds__(256) void kconv_k(const float* __restrict__ K,
                                               _Float16* __restrict__ Ktf) {
    __shared__ float tile[32 * 256];           // 32 KB, swizzled cols
    int kt  = blockIdx.x >> 2;                 // 0..991
    int nb4 = blockIdx.x & 3;                  // 0..3 (256-col tile)
    int tid = threadIdx.x;
    int lane = tid & 63, w = tid >> 6;

    // phase 1: 32 rows x 256 cols, fully coalesced
    {
        const float* src = K + ((size_t)kt * 32) * ND + nb4 * 256;
        #pragma unroll
        for (int i = 0; i < 8; ++i) {
            int r = i * 4 + w;
            int x = lane * 4;
            int xs = x ^ (((r >> 3) & 1) << 4);       // swizzle: flip bit4 by k_hi parity
            float4 v = *(const float4*)(src + (size_t)r * ND + x);
            *(float4*)&tile[r * 256 + xs] = v;
        }
    }
    __syncthreads();

    // phase 2: gather fragment columns, convert, store
    int kl0 = (lane >> 4) * 8;
    int swz = ((lane >> 4) & 1) << 4;                 // constant across j (k>>3 = lane>>4)
    #pragma unroll
    for (int i = 0; i < 4; ++i) {
        int ns_local = i * 4 + w;                     // 0..15
        int nl = ns_local * 16 + (lane & 15);         // col within tile
        int xsw = nl ^ swz;
        half8 v;
        #pragma unroll
        for (int j = 0; j < 8; ++j) v[j] = (_Float16)tile[(kl0 + j) * 256 + xsw];
        int ns = nb4 * 16 + ns_local;
        size_t unit = ((size_t)ns * KT32 + kt) * 64 + lane;
        *(half8*)(Ktf + unit * 8) = v;
    }
}

// ---- GEMM: P[ks][b][n] = sum over block's 256-k chunk of (w*h) @ B ----
// grid (4 n-tiles of 256, 124 k-splits) = 496 blocks, 256 thr (all resident).
// Wave = M64 x N64 (4 n-subtiles): A LDS reads halved per MFMA.
// B fully preloaded: 32 half8 regs (32 outstanding 1KB loads). No VGPR cap.
__global__ __launch_bounds__(256) void gemm_k(
    const float* __restrict__ h, const _Float16* __restrict__ Ktf,
    const float* __restrict__ W, float* __restrict__ P, int step)
{
    __shared__ _Float16 lds_a[64 * 256];   // 32 KiB; half8-index: p*64 + b (p = s*4+q)
    int nb = blockIdx.x;                   // 0..3
    int ks = blockIdx.y;                   // 0..123
    int tid = threadIdx.x;
    int l = tid & 63, w = tid >> 6;
    int o = ks >> 2;
    int d_base = (ks & 3) * 256;

    // ---- stage A: fp32 h * w  ->  fp16, frag-ordered ----
    {
        int b = tid >> 2, u = tid & 3;
        float wv = W[((size_t)b * NSTEPS + step) * NO + o];
        const float* hb = h + (size_t)b * ND + d_base;
        #pragma unroll
        for (int li = 0; li < 8; ++li) {
            int p = li * 4 + u;                       // p = s*4+q, d offset = p*8
            float4 x0 = *(const float4*)(hb + p * 8);
            float4 x1 = *(const float4*)(hb + p * 8 + 4);
            half8 v;
            v[0] = (_Float16)(x0.x * wv); v[1] = (_Float16)(x0.y * wv);
            v[2] = (_Float16)(x0.z * wv); v[3] = (_Float16)(x0.w * wv);
            v[4] = (_Float16)(x1.x * wv); v[5] = (_Float16)(x1.y * wv);
            v[6] = (_Float16)(x1.z * wv); v[7] = (_Float16)(x1.w * wv);
            *(half8*)&lds_a[(size_t)(p * 64 + b) * 8] = v;
        }
    }
    __syncthreads();

    int ml = l & 15, q = l >> 4;
    int ns0 = nb * 16 + w * 4;                // four n-subtiles of 16 per wave
    const half8* Ap = (const half8*)lds_a;

    // preload ALL B fragments: 4 subtiles x 8 k-steps (static indices only)
    half8 breg[4][8];
    #pragma unroll
    for (int t = 0; t < 4; ++t) {
        const half8* bp = (const half8*)Ktf
            + ((size_t)(ns0 + t) * KT32 + (size_t)ks * KC32) * 64 + l;
        #pragma unroll
        for (int s = 0; s < 8; ++s) breg[t][s] = bp[(size_t)s * 64];
    }

    floatx4 acc[4][4] = {};
    #pragma unroll
    for (int s = 0; s < 8; ++s) {
        int abase = (s * 4 + q) * 64 + ml;
        half8 a0 = Ap[abase];
        half8 a1 = Ap[abase + 16];
        half8 a2 = Ap[abase + 32];
        half8 a3 = Ap[abase + 48];
        #pragma unroll
        for (int t = 0; t < 4; ++t) {
            acc[t][0] = __builtin_amdgcn_mfma_f32_16x16x32_f16(a0, breg[t][s], acc[t][0], 0, 0, 0);
            acc[t][1] = __builtin_amdgcn_mfma_f32_16x16x32_f16(a1, breg[t][s], acc[t][1], 0, 0, 0);
            acc[t][2] = __builtin_amdgcn_mfma_f32_16x16x32_f16(a2, breg[t][s], acc[t][2], 0, 0, 0);
            acc[t][3] = __builtin_amdgcn_mfma_f32_16x16x32_f16(a3, breg[t][s], acc[t][3], 0, 0, 0);
        }
    }

    // ---- epilogue: C/D col = l&15, row = (l>>4)*4 + r (verified mapping) ----
    float* Pks = P + (size_t)ks * (NB * ND);
    #pragma unroll
    for (int t = 0; t < 4; ++t) {
        int n = (ns0 + t) * 16 + ml;
        #pragma unroll
        for (int mt = 0; mt < 4; ++mt) {
            #pragma unroll
            for (int r = 0; r < 4; ++r) {
                int b = mt * 16 + q * 4 + r;
                Pks[(size_t)b * ND + n] = acc[t][mt][r];
            }
        }
    }
}

// ---- reduce KS partials + gated update: wave-split ks reduction ----
// 1024 blocks x 256 thr. Block owns 64 contiguous outputs (one b each).
// Wave w sums ks in [31w, 31w+31); lanes map to consecutive outputs
// (coalesced 256B wave-loads). LDS tree combine, first 64 lanes finalize.
__global__ void update_k(const float* __restrict__ hin, const float* __restrict__ P,
                         const float* __restrict__ operands, float* __restrict__ hout,
                         int step)
{
    __shared__ float red[256];
    int tid = threadIdx.x;
    int w = tid >> 6, o = tid & 63;
    int gbase = blockIdx.x * 64;          // 64 outputs per block, same b
    int g = gbase + o;
    const float* p = P + (size_t)(w * 31) * (NB * ND) + g;
    float s = 0.f;
    #pragma unroll
    for (int i = 0; i < 31; ++i) s += p[(size_t)i * (NB * ND)];
    red[tid] = s;
    __syncthreads();
    if (tid < 64) {
        float tot = red[tid] + red[tid + 64] + red[tid + 128] + red[tid + 192];
        int b = g >> 10;
        float gl = operands[((size_t)b * NSTEPS + step) * 4 + 3];
        float gt = 1.0f / (1.0f + expf(-gl));
        hout[g] = gt * tot + (1.0f - gt) * hin[g];
    }
}

extern "C" void kernel_launch(void* const* d_in, const int* in_sizes, int n_in,
                              void* d_out, int out_size, void* d_ws, size_t ws_size,
                              hipStream_t stream)
{
    const float* logits   = (const float*)d_in[0];  // (64,16,31)
    const float* operands = (const float*)d_in[1];  // (64,16,4)
    const float* signal   = (const float*)d_in[2];  // (64,1024)
    const float* opk      = (const float*)d_in[3];  // (31,1024,1024)
    float* out = (float*)d_out;
    char* ws = (char*)d_ws;

    size_t offW = 0;                                   // 128 KB
    size_t offP = 131072;                              // KS*64*1024*4 = 31 MB
    size_t offH = offP + (size_t)KS * NB * ND * 4;
    size_t offK = offH + 2ull * NB * ND * 4;           // Ktf: 62 MiB fp16

    float*    W  = (float*)(ws + offW);
    float*    P  = (float*)(ws + offP);
    float*    h0 = (float*)(ws + offH);
    float*    h1 = h0 + NB * ND;
    _Float16* Ktf = (_Float16*)(ws + offK);

    softmax_k<<<dim3(4), 256, 0, stream>>>(logits, W);
    kconv_k<<<dim3(3968), 256, 0, stream>>>(opk, Ktf);

    const float* hc = signal;
    float* hn = h0;
    for (int t = 0; t < NSTEPS; ++t) {
        gemm_k<<<dim3(4, KS), 256, 0, stream>>>(hc, Ktf, W, P, t);
        float* dst = (t == NSTEPS - 1) ? out : hn;
        update_k<<<dim3(1024), 256, 0, stream>>>(hc, P, operands, dst, t);
        hc = dst;
        hn = (hn == h0) ? h1 : h0;
    }
}

// Round 5
// 524.647 us; speedup vs baseline: 1.3014x; 1.1169x over previous
//
#include <hip/hip_runtime.h>
#include <cstddef>
#include <cstdint>

#define NB 64
#define ND 1024
#define NO 31
#define NSTEPS 16
#define KS 62            // k-splits in P (k-chunk = 512 k-units, never crosses an opcode)
#define KT32 992         // total K32 steps = 31*1024/32
#define KC32 16          // K32 steps per block (two 8-step halves, one per wave-pair)

typedef _Float16 half8 __attribute__((ext_vector_type(8)));
typedef float floatx4 __attribute__((ext_vector_type(4)));

// ---------------- softmax over opcode logits: W[b][t][o] ----------------
__global__ void softmax_k(const float* __restrict__ logits, float* __restrict__ W) {
    int row = blockIdx.x * blockDim.x + threadIdx.x;  // row = b*16 + t
    if (row >= NB * NSTEPS) return;
    const float* x = logits + (size_t)row * NO;
    float m = -1e30f;
    for (int o = 0; o < NO; ++o) m = fmaxf(m, x[o]);
    float e[NO]; float s = 0.f;
    for (int o = 0; o < NO; ++o) { e[o] = expf(x[o] - m); s += e[o]; }
    float inv = 1.0f / s;
    float* wo = W + (size_t)row * NO;
    for (int o = 0; o < NO; ++o) wo[o] = e[o] * inv;
}

// ---- kconv v2: coalesced tile transpose ----
// Block = one kt (32 k-rows, never crosses opcode) x 256 n-cols.
// Phase 1: float4 row loads (1KB/wave contiguous) -> LDS, bit4-XOR swizzle.
// Phase 2: column gather (2-way bank alias = free), cvt fp16, contiguous
// 1KB wave-stores in fragment order.
// Ktf half8 unit (ns*KT32 + kt)*64 + l holds k = kt*32 + (l>>4)*8 + j,
// n = ns*16 + (l&15); value = K[k*1024 + n].
__global__ __launch_bounds__(256) void kconv_k(const float* __restrict__ K,
                                               _Float16* __restrict__ Ktf) {
    __shared__ float tile[32 * 256];           // 32 KB, swizzled cols
    int kt  = blockIdx.x >> 2;                 // 0..991
    int nb4 = blockIdx.x & 3;                  // 0..3 (256-col tile)
    int tid = threadIdx.x;
    int lane = tid & 63, w = tid >> 6;

    // phase 1: 32 rows x 256 cols, fully coalesced
    {
        const float* src = K + ((size_t)kt * 32) * ND + nb4 * 256;
        #pragma unroll
        for (int i = 0; i < 8; ++i) {
            int r = i * 4 + w;
            int x = lane * 4;
            int xs = x ^ (((r >> 3) & 1) << 4);       // swizzle: flip bit4 by k_hi parity
            float4 v = *(const float4*)(src + (size_t)r * ND + x);
            *(float4*)&tile[r * 256 + xs] = v;
        }
    }
    __syncthreads();

    // phase 2: gather fragment columns, convert, store
    int kl0 = (lane >> 4) * 8;
    int swz = ((lane >> 4) & 1) << 4;                 // constant across j (k>>3 = lane>>4)
    #pragma unroll
    for (int i = 0; i < 4; ++i) {
        int ns_local = i * 4 + w;                     // 0..15
        int nl = ns_local * 16 + (lane & 15);         // col within tile
        int xsw = nl ^ swz;
        half8 v;
        #pragma unroll
        for (int j = 0; j < 8; ++j) v[j] = (_Float16)tile[(kl0 + j) * 256 + xsw];
        int ns = nb4 * 16 + ns_local;
        size_t unit = ((size_t)ns * KT32 + kt) * 64 + lane;
        *(half8*)(Ktf + unit * 8) = v;
    }
}

// ---- GEMM: P[ks][b][n] = sum over block's 512-k chunk of (w*h) @ B ----
// grid (4 n-tiles of 256, 62 k-splits) = 248 blocks, 512 thr (8 waves).
// Wave = M64 x N64; wave-pair (kh=0/1) splits the 512-k chunk in halves;
// kh=1 dumps acc to LDS (reusing A buffer), kh=0 adds + stores -> P traffic halved.
__global__ __launch_bounds__(512) void gemm_k(
    const float* __restrict__ h, const _Float16* __restrict__ Ktf,
    const float* __restrict__ W, float* __restrict__ P, int step)
{
    __shared__ _Float16 lds_a[64 * 512];   // 64 KiB; half8-index: p*64 + b, p in [0,64)
    int nb = blockIdx.x;                   // 0..3
    int ks = blockIdx.y;                   // 0..61
    int tid = threadIdx.x;                 // 0..511
    int l = tid & 63, w = tid >> 6;        // w 0..7
    int o = ks >> 1;
    int d_base = (ks & 1) * 512;

    // ---- stage A: fp32 h * w  ->  fp16, frag-ordered (64 b x 512 d) ----
    {
        int b = tid >> 3, u = tid & 7;
        float wv = W[((size_t)b * NSTEPS + step) * NO + o];
        const float* hb = h + (size_t)b * ND + d_base;
        #pragma unroll
        for (int li = 0; li < 8; ++li) {
            int p = li * 8 + u;                       // p in [0,64), d offset = p*8
            float4 x0 = *(const float4*)(hb + p * 8);
            float4 x1 = *(const float4*)(hb + p * 8 + 4);
            half8 v;
            v[0] = (_Float16)(x0.x * wv); v[1] = (_Float16)(x0.y * wv);
            v[2] = (_Float16)(x0.z * wv); v[3] = (_Float16)(x0.w * wv);
            v[4] = (_Float16)(x1.x * wv); v[5] = (_Float16)(x1.y * wv);
            v[6] = (_Float16)(x1.z * wv); v[7] = (_Float16)(x1.w * wv);
            *(half8*)&lds_a[(size_t)(p * 64 + b) * 8] = v;
        }
    }
    __syncthreads();

    int ml = l & 15, q = l >> 4;
    int wn = w & 3, kh = w >> 2;
    int ns0 = nb * 16 + wn * 4;               // four n-subtiles of 16 per wave
    const half8* Ap = (const half8*)lds_a;

    // preload ALL B fragments for this wave's k-half (static indices only)
    half8 breg[4][8];
    #pragma unroll
    for (int t = 0; t < 4; ++t) {
        const half8* bp = (const half8*)Ktf
            + ((size_t)(ns0 + t) * KT32 + (size_t)(ks * KC32 + kh * 8)) * 64 + l;
        #pragma unroll
        for (int s = 0; s < 8; ++s) breg[t][s] = bp[(size_t)s * 64];
    }

    floatx4 acc[4][4] = {};
    #pragma unroll
    for (int s = 0; s < 8; ++s) {
        int abase = ((kh * 8 + s) * 4 + q) * 64 + ml;
        half8 a0 = Ap[abase];
        half8 a1 = Ap[abase + 16];
        half8 a2 = Ap[abase + 32];
        half8 a3 = Ap[abase + 48];
        #pragma unroll
        for (int t = 0; t < 4; ++t) {
            acc[t][0] = __builtin_amdgcn_mfma_f32_16x16x32_f16(a0, breg[t][s], acc[t][0], 0, 0, 0);
            acc[t][1] = __builtin_amdgcn_mfma_f32_16x16x32_f16(a1, breg[t][s], acc[t][1], 0, 0, 0);
            acc[t][2] = __builtin_amdgcn_mfma_f32_16x16x32_f16(a2, breg[t][s], acc[t][2], 0, 0, 0);
            acc[t][3] = __builtin_amdgcn_mfma_f32_16x16x32_f16(a3, breg[t][s], acc[t][3], 0, 0, 0);
        }
    }

    // ---- pairwise k-half reduce via LDS (reuse lds_a: 16 slots x 256 float4 = 64 KB) ----
    __syncthreads();                          // all A reads done
    floatx4* lred = (floatx4*)lds_a;
    if (kh == 1) {
        #pragma unroll
        for (int t = 0; t < 4; ++t)
            #pragma unroll
            for (int mt = 0; mt < 4; ++mt)
                lred[(t * 4 + mt) * 256 + wn * 64 + l] = acc[t][mt];
    }
    __syncthreads();
    if (kh == 0) {
        // C/D mapping: col = l&15, row = (l>>4)*4 + r (verified)
        float* Pks = P + (size_t)ks * (NB * ND);
        #pragma unroll
        for (int t = 0; t < 4; ++t) {
            int n = (ns0 + t) * 16 + ml;
            #pragma unroll
            for (int mt = 0; mt < 4; ++mt) {
                floatx4 other = lred[(t * 4 + mt) * 256 + wn * 64 + l];
                #pragma unroll
                for (int r = 0; r < 4; ++r) {
                    int b = mt * 16 + q * 4 + r;
                    Pks[(size_t)b * ND + n] = acc[t][mt][r] + other[r];
                }
            }
        }
    }
}

// ---- reduce KS=62 partials + gated update ----
// 512 blocks x 256 thr. Block owns 128 contiguous outputs (same b).
// Wave-pairs: waves {0,1} sum ks [0,31), waves {2,3} sum ks [31,62),
// each wave covers 64 of the 128 outputs (coalesced 256B wave-loads).
__global__ void update_k(const float* __restrict__ hin, const float* __restrict__ P,
                         const float* __restrict__ operands, float* __restrict__ hout,
                         int step)
{
    __shared__ float red[256];
    int tid = threadIdx.x;
    int w = tid >> 6, lane = tid & 63;
    int j = (w & 1) * 64 + lane;              // output slot 0..127
    int g = blockIdx.x * 128 + j;
    const float* p = P + (size_t)((w >> 1) * 31) * (NB * ND) + g;
    float s = 0.f;
    #pragma unroll
    for (int i = 0; i < 31; ++i) s += p[(size_t)i * (NB * ND)];
    red[(w >> 1) * 128 + j] = s;
    __syncthreads();
    if (tid < 128) {
        float tot = red[tid] + red[tid + 128];
        int g2 = blockIdx.x * 128 + tid;
        int b = g2 >> 10;
        float gl = operands[((size_t)b * NSTEPS + step) * 4 + 3];
        float gt = 1.0f / (1.0f + expf(-gl));
        hout[g2] = gt * tot + (1.0f - gt) * hin[g2];
    }
}

extern "C" void kernel_launch(void* const* d_in, const int* in_sizes, int n_in,
                              void* d_out, int out_size, void* d_ws, size_t ws_size,
                              hipStream_t stream)
{
    const float* logits   = (const float*)d_in[0];  // (64,16,31)
    const float* operands = (const float*)d_in[1];  // (64,16,4)
    const float* signal   = (const float*)d_in[2];  // (64,1024)
    const float* opk      = (const float*)d_in[3];  // (31,1024,1024)
    float* out = (float*)d_out;
    char* ws = (char*)d_ws;

    size_t offW = 0;                                   // 128 KB
    size_t offP = 131072;                              // KS*64*1024*4 = 15.5 MB
    size_t offH = offP + (size_t)KS * NB * ND * 4;
    size_t offK = offH + 2ull * NB * ND * 4;           // Ktf: 62 MiB fp16

    float*    W  = (float*)(ws + offW);
    float*    P  = (float*)(ws + offP);
    float*    h0 = (float*)(ws + offH);
    float*    h1 = h0 + NB * ND;
    _Float16* Ktf = (_Float16*)(ws + offK);

    softmax_k<<<dim3(4), 256, 0, stream>>>(logits, W);
    kconv_k<<<dim3(3968), 256, 0, stream>>>(opk, Ktf);

    const float* hc = signal;
    float* hn = h0;
    for (int t = 0; t < NSTEPS; ++t) {
        gemm_k<<<dim3(4, KS), 512, 0, stream>>>(hc, Ktf, W, P, t);
        float* dst = (t == NSTEPS - 1) ? out : hn;
        update_k<<<dim3(512), 256, 0, stream>>>(hc, P, operands, dst, t);
        hc = dst;
        hn = (hn == h0) ? h1 : h0;
    }
}